// Round 3
// baseline (707.354 us; speedup 1.0000x reference)
//
#include <hip/hip_runtime.h>

// Problem constants (match reference)
#define N_PTS   1000000
#define C_DIM   128
#define B_DIM   8
#define Y_DIM   468
#define X_DIM   468
#define YX      (Y_DIM * X_DIM)         // 219024
#define KSPACE  (B_DIM * YX)            // 1752192 dense key space

// Scan config
#define WG   256
#define EPT  8
#define EPB  (WG * EPT)                 // 2048 elements per scan block
#define NBLK ((KSPACE + EPB - 1) / EPB) // 856

#define SINGLE_FLAG (1ull << 63)

__device__ __forceinline__ unsigned long long shfl_up_u64(unsigned long long v, int delta) {
    unsigned lo = (unsigned)v;
    unsigned hi = (unsigned)(v >> 32);
    lo = __shfl_up(lo, delta, 64);
    hi = __shfl_up(hi, delta, 64);
    return ((unsigned long long)hi << 32) | lo;
}

// ---------------------------------------------------------------- zero
__global__ void zero_u32(unsigned* __restrict__ p, int n) {
    int i = blockIdx.x * blockDim.x + threadIdx.x;
    if (i < n) p[i] = 0u;
}

// ---------------------------------------------------------------- histogram + key cache
__global__ void hist_kernel(const int* __restrict__ idx, unsigned* __restrict__ cnt,
                            unsigned* __restrict__ keys, int n) {
    int i = blockIdx.x * blockDim.x + threadIdx.x;
    if (i >= n) return;
    int4 v = ((const int4*)idx)[i];          // (b, z, y, x)
    unsigned key = (unsigned)(v.x * YX + v.z * X_DIM + v.w);
    keys[i] = key;
    atomicAdd(&cnt[key], 1u);
}

// ---------------------------------------------------------------- scan pass 1: per-block exclusive scan of (presence<<32)|count
// pairs[k] = exclusive prefix within block, bit63 = (cnt[k]==1)
__global__ void scan1_kernel(const unsigned* __restrict__ cnt,
                             unsigned long long* __restrict__ pairs,
                             unsigned long long* __restrict__ bsums, int K) {
    int base = blockIdx.x * EPB + threadIdx.x * EPT;
    unsigned long long p[EPT];
    unsigned cc[EPT];
    unsigned long long run = 0;
#pragma unroll
    for (int j = 0; j < EPT; ++j) {
        int k = base + j;
        unsigned c = (k < K) ? cnt[k] : 0u;
        cc[j] = c;
        unsigned long long pr = (unsigned long long)c | ((unsigned long long)(c ? 1u : 0u) << 32);
        p[j] = run;                           // exclusive within thread
        run += pr;
    }
    unsigned long long tot = run;
    // inclusive wave scan of thread totals
    int lane = threadIdx.x & 63;
    unsigned long long v = tot;
#pragma unroll
    for (int d = 1; d < 64; d <<= 1) {
        unsigned long long nv = shfl_up_u64(v, d);
        if (lane >= d) v += nv;
    }
    __shared__ unsigned long long wsum[WG / 64];
    int wid = threadIdx.x >> 6;
    if (lane == 63) wsum[wid] = v;
    __syncthreads();
    unsigned long long wexcl = 0;
    for (int w = 0; w < wid; ++w) wexcl += wsum[w];
    unsigned long long texcl = wexcl + v - tot;   // exclusive across threads in block
#pragma unroll
    for (int j = 0; j < EPT; ++j) {
        int k = base + j;
        if (k < K)
            pairs[k] = (texcl + p[j]) | (cc[j] == 1u ? SINGLE_FLAG : 0ull);
    }
    if (threadIdx.x == WG - 1) bsums[blockIdx.x] = wexcl + v;  // block total
}

// ---------------------------------------------------------------- scan pass 2: exclusive scan of block sums (single block, nb <= 1024)
__global__ void scan2_kernel(unsigned long long* __restrict__ bsums, int nb) {
    int t = threadIdx.x;
    unsigned long long orig = (t < nb) ? bsums[t] : 0ull;
    unsigned long long v = orig;
    int lane = t & 63;
#pragma unroll
    for (int d = 1; d < 64; d <<= 1) {
        unsigned long long nv = shfl_up_u64(v, d);
        if (lane >= d) v += nv;
    }
    __shared__ unsigned long long ws[1024 / 64];
    int wid = t >> 6;
    if (lane == 63) ws[wid] = v;
    __syncthreads();
    unsigned long long wexcl = 0;
    for (int w = 0; w < wid; ++w) wexcl += ws[w];
    if (t < nb) bsums[t] = wexcl + v - orig;      // exclusive
    if (t == 1023) {                              // grand total -> bsums[nb]
        unsigned long long tt = 0;
        for (int w = 0; w < 1024 / 64; ++w) tt += ws[w];
        bsums[nb] = tt;
    }
}

// ---------------------------------------------------------------- build multi-bucket worklist {start, end, key, rank}
__global__ void uniq_kernel(const unsigned* __restrict__ cnt,
                            const unsigned long long* __restrict__ pairs,
                            const unsigned long long* __restrict__ bsums,
                            uint4* __restrict__ wl, unsigned* __restrict__ wlcnt, int K) {
    int k = blockIdx.x * blockDim.x + threadIdx.x;
    if (k >= K) return;
    unsigned c = cnt[k];
    if (c < 2) return;                                   // singletons handled point-driven
    unsigned long long pr = (pairs[k] & ~SINGLE_FLAG) + bsums[k >> 11];  // EPB = 2048
    unsigned r     = (unsigned)(pr >> 32) & 0x3FFFFFFFu; // rank
    unsigned start = (unsigned)pr;                       // bucket start
    unsigned slot  = atomicAdd(wlcnt, 1u);
    wl[slot] = make_uint4(start, start + c, (unsigned)k, r);
}

// ---------------------------------------------------------------- scatter point ids into buckets (multi only)
__global__ void scatter_kernel(const unsigned* __restrict__ keys,
                               const unsigned long long* __restrict__ pairs,
                               const unsigned long long* __restrict__ bsums,
                               unsigned* __restrict__ cursor,
                               unsigned* __restrict__ pointIds, int n) {
    int i = blockIdx.x * blockDim.x + threadIdx.x;
    if (i >= n) return;
    unsigned k = keys[i];
    unsigned long long pr = pairs[k];
    if (pr >> 63) return;                                // singleton — no pid list needed
    unsigned start = (unsigned)(pr + bsums[k >> 11]);
    unsigned off = atomicAdd(&cursor[k], 1u);
    pointIds[start + off] = (unsigned)i;
}

// ---------------------------------------------------------------- point-driven: singleton buckets copy their own row
__global__ void __launch_bounds__(256)
point_kernel(const float* __restrict__ feat, const unsigned* __restrict__ keys,
             const unsigned long long* __restrict__ pairs,
             const unsigned long long* __restrict__ bsums,
             float* __restrict__ outF, float* __restrict__ outI, int n) {
    int lane = threadIdx.x & 63;
    int wid  = threadIdx.x >> 6;
    int half = lane >> 5;                 // which of the 2 points this lane serves
    int sub  = lane & 31;                 // float4 slot within the row
    long p = (long)blockIdx.x * 8 + wid * 2 + half;
    if (p >= n) return;
    unsigned key = keys[p];
    unsigned long long pr = pairs[key] + bsums[key >> 11];
    if (!(pr >> 63)) return;              // not a singleton bucket
    unsigned rank = (unsigned)(pr >> 32) & 0x3FFFFFFFu;
    float4 v = ((const float4*)(feat + (size_t)p * C_DIM))[sub];
    ((float4*)(outF + (size_t)rank * C_DIM))[sub] = v;
    if (sub == 0) {
        unsigned bb  = key / YX;
        unsigned rem = key % YX;
        outI[(size_t)rank * 3 + 0] = (float)bb;
        outI[(size_t)rank * 3 + 1] = (float)(rem / X_DIM);
        outI[(size_t)rank * 3 + 2] = (float)(rem % X_DIM);
    }
}

// ---------------------------------------------------------------- row-driven: multi buckets gather+sum (grid-stride over worklist)
__global__ void __launch_bounds__(256)
multi_kernel(const float* __restrict__ feat, const unsigned* __restrict__ pointIds,
             const uint4* __restrict__ wl, const unsigned* __restrict__ wlcnt,
             float* __restrict__ outF, float* __restrict__ outI) {
    int lane = threadIdx.x & 63;
    int wid  = threadIdx.x >> 6;
    int half = lane >> 5;
    int sub  = lane & 31;
    long m = (long)*wlcnt;
    long base   = (long)blockIdx.x * 8 + wid * 2 + half;
    long stride = (long)gridDim.x * 8;
    for (long r = base; r < m; r += stride) {
        uint4 d = wl[r];
        float4 acc = make_float4(0.f, 0.f, 0.f, 0.f);
        for (unsigned j = d.x; j < d.y; ++j) {
            unsigned pid = pointIds[j];
            float4 v = ((const float4*)(feat + (size_t)pid * C_DIM))[sub];
            acc.x += v.x; acc.y += v.y; acc.z += v.z; acc.w += v.w;
        }
        ((float4*)(outF + (size_t)d.w * C_DIM))[sub] = acc;
        if (sub == 0) {
            unsigned key = d.z;
            unsigned bb  = key / YX;
            unsigned rem = key % YX;
            outI[(size_t)d.w * 3 + 0] = (float)bb;
            outI[(size_t)d.w * 3 + 1] = (float)(rem / X_DIM);
            outI[(size_t)d.w * 3 + 2] = (float)(rem % X_DIM);
        }
    }
}

// ---------------------------------------------------------------- pad rows [nU, n): zeros + (-1, 467, 467)
__global__ void __launch_bounds__(256)
pad_kernel(const unsigned long long* __restrict__ total,
           float* __restrict__ outF, float* __restrict__ outI, int n) {
    int lane = threadIdx.x & 63;
    int wid  = threadIdx.x >> 6;
    int half = lane >> 5;
    int sub  = lane & 31;
    long nU = (long)(unsigned)((*total) >> 32);
    long base   = nU + (long)blockIdx.x * 8 + wid * 2 + half;
    long stride = (long)gridDim.x * 8;
    for (long r = base; r < n; r += stride) {
        ((float4*)(outF + (size_t)r * C_DIM))[sub] = make_float4(0.f, 0.f, 0.f, 0.f);
        if (sub == 0) {
            outI[(size_t)r * 3 + 0] = -1.0f;
            outI[(size_t)r * 3 + 1] = 467.0f;   // (-1 % YX) // X per numpy floor-mod
            outI[(size_t)r * 3 + 2] = 467.0f;
        }
    }
}

extern "C" void kernel_launch(void* const* d_in, const int* in_sizes, int n_in,
                              void* d_out, int out_size, void* d_ws, size_t ws_size,
                              hipStream_t stream) {
    const float* feat = (const float*)d_in[0];
    const int*   idx  = (const int*)d_in[1];
    const int n = in_sizes[0] / C_DIM;   // 1,000,000
    const int K = KSPACE;

    // workspace layout (256B aligned slices)
    char* ws = (char*)d_ws;
    size_t off = 0;
    auto take = [&](size_t bytes) {
        size_t cur = off;
        off = (off + bytes + 255) & ~(size_t)255;
        return cur;
    };
    size_t o_cnt    = take((size_t)K * 4);        // count per key        (K*4 is 256B-multiple)
    size_t o_cursor = take((size_t)K * 4);        // scatter cursors      (contiguous w/ cnt)
    size_t o_wlcnt  = take(256);                  // worklist counter     (contiguous w/ cursor)
    size_t o_keys   = take((size_t)n * 4);        // cached keys per point
    size_t o_pairs  = take((size_t)K * 8);        // scan pairs + singleton flag
    size_t o_bsums  = take((size_t)(NBLK + 1) * 8);
    size_t o_pids   = take((size_t)n * 4);        // point ids (multi buckets only)
    size_t o_wl     = take((size_t)(n / 2 + 1) * 16);  // worklist {start,end,key,rank}

    unsigned*           cnt    = (unsigned*)(ws + o_cnt);
    unsigned*           cursor = (unsigned*)(ws + o_cursor);
    unsigned*           wlcnt  = (unsigned*)(ws + o_wlcnt);
    unsigned*           keys   = (unsigned*)(ws + o_keys);
    unsigned long long* pairs  = (unsigned long long*)(ws + o_pairs);
    unsigned long long* bsums  = (unsigned long long*)(ws + o_bsums);
    unsigned*           pids   = (unsigned*)(ws + o_pids);
    uint4*              wl     = (uint4*)(ws + o_wl);

    float* outF = (float*)d_out;
    float* outI = outF + (size_t)n * C_DIM;

    // 1. zero cnt + cursor + wlcnt (contiguous)
    {
        int m = 2 * K + 64;
        zero_u32<<<(m + 255) / 256, 256, 0, stream>>>(cnt, m);
    }
    // 2. histogram + cache keys
    hist_kernel<<<(n + 255) / 256, 256, 0, stream>>>(idx, cnt, keys, n);
    // 3-4. two-level exclusive scan of (presence, count) pairs
    scan1_kernel<<<NBLK, WG, 0, stream>>>(cnt, pairs, bsums, K);
    scan2_kernel<<<1, 1024, 0, stream>>>(bsums, NBLK);
    // 5. multi-bucket worklist
    uniq_kernel<<<(K + 255) / 256, 256, 0, stream>>>(cnt, pairs, bsums, wl, wlcnt, K);
    // 6. scatter point ids (multi buckets only)
    scatter_kernel<<<(n + 255) / 256, 256, 0, stream>>>(keys, pairs, bsums, cursor, pids, n);
    // 7. point-driven singleton copy
    point_kernel<<<(n + 7) / 8, 256, 0, stream>>>(feat, keys, pairs, bsums, outF, outI, n);
    // 8. row-driven multi gather+sum
    multi_kernel<<<2048, 256, 0, stream>>>(feat, pids, wl, wlcnt, outF, outI);
    // 9. pad tail rows
    pad_kernel<<<2048, 256, 0, stream>>>(bsums + NBLK, outF, outI, n);
}

// Round 4
// 399.238 us; speedup vs baseline: 1.7718x; 1.7718x over previous
//
#include <hip/hip_runtime.h>

// Problem constants (match reference)
#define N_PTS   1000000
#define C_DIM   128
#define B_DIM   8
#define Y_DIM   468
#define X_DIM   468
#define YX      (Y_DIM * X_DIM)         // 219024
#define KSPACE  (B_DIM * YX)            // 1752192 dense key space

// Scan config
#define WG   256
#define EPT  8
#define EPB  (WG * EPT)                 // 2048 elements per scan block
#define NBLK ((KSPACE + EPB - 1) / EPB) // 856

// 3-field packed scan element: [0:21) point-count, [21:42) unique-count, [42:63) multi-count
#define F_BITS 21
#define F_MASK 0x1FFFFFu
#define SINGLE_FLAG (1ull << 63)

__device__ __forceinline__ unsigned long long shfl_up_u64(unsigned long long v, int delta) {
    unsigned lo = (unsigned)v;
    unsigned hi = (unsigned)(v >> 32);
    lo = __shfl_up(lo, delta, 64);
    hi = __shfl_up(hi, delta, 64);
    return ((unsigned long long)hi << 32) | lo;
}

// ---------------------------------------------------------------- zero
__global__ void zero_u32(unsigned* __restrict__ p, int n) {
    int i = blockIdx.x * blockDim.x + threadIdx.x;
    if (i < n) p[i] = 0u;
}

// ---------------------------------------------------------------- histogram + key cache
__global__ void hist_kernel(const int* __restrict__ idx, unsigned* __restrict__ cnt,
                            unsigned* __restrict__ keys, int n) {
    int i = blockIdx.x * blockDim.x + threadIdx.x;
    if (i >= n) return;
    int4 v = ((const int4*)idx)[i];          // (b, z, y, x)
    unsigned key = (unsigned)(v.x * YX + v.z * X_DIM + v.w);
    keys[i] = key;
    atomicAdd(&cnt[key], 1u);
}

// ---------------------------------------------------------------- scan pass 1: per-block exclusive scan of packed (count|unique|multi)
// pairs[k] = exclusive prefix within block, bit63 = (cnt[k]==1)
__global__ void scan1_kernel(const unsigned* __restrict__ cnt,
                             unsigned long long* __restrict__ pairs,
                             unsigned long long* __restrict__ bsums, int K) {
    int base = blockIdx.x * EPB + threadIdx.x * EPT;
    unsigned long long p[EPT];
    unsigned cc[EPT];
    unsigned long long run = 0;
#pragma unroll
    for (int j = 0; j < EPT; ++j) {
        int k = base + j;
        unsigned c = (k < K) ? cnt[k] : 0u;
        cc[j] = c;
        unsigned long long pr = (unsigned long long)c
                              | ((unsigned long long)(c ? 1u : 0u) << F_BITS)
                              | ((unsigned long long)(c >= 2u ? 1u : 0u) << (2 * F_BITS));
        p[j] = run;                           // exclusive within thread
        run += pr;
    }
    unsigned long long tot = run;
    // inclusive wave scan of thread totals
    int lane = threadIdx.x & 63;
    unsigned long long v = tot;
#pragma unroll
    for (int d = 1; d < 64; d <<= 1) {
        unsigned long long nv = shfl_up_u64(v, d);
        if (lane >= d) v += nv;
    }
    __shared__ unsigned long long wsum[WG / 64];
    int wid = threadIdx.x >> 6;
    if (lane == 63) wsum[wid] = v;
    __syncthreads();
    unsigned long long wexcl = 0;
    for (int w = 0; w < wid; ++w) wexcl += wsum[w];
    unsigned long long texcl = wexcl + v - tot;   // exclusive across threads in block
#pragma unroll
    for (int j = 0; j < EPT; ++j) {
        int k = base + j;
        if (k < K)
            pairs[k] = (texcl + p[j]) | (cc[j] == 1u ? SINGLE_FLAG : 0ull);
    }
    if (threadIdx.x == WG - 1) bsums[blockIdx.x] = wexcl + v;  // block total
}

// ---------------------------------------------------------------- scan pass 2: exclusive scan of block sums (single block, nb <= 1024)
__global__ void scan2_kernel(unsigned long long* __restrict__ bsums, int nb) {
    int t = threadIdx.x;
    unsigned long long orig = (t < nb) ? bsums[t] : 0ull;
    unsigned long long v = orig;
    int lane = t & 63;
#pragma unroll
    for (int d = 1; d < 64; d <<= 1) {
        unsigned long long nv = shfl_up_u64(v, d);
        if (lane >= d) v += nv;
    }
    __shared__ unsigned long long ws[1024 / 64];
    int wid = t >> 6;
    if (lane == 63) ws[wid] = v;
    __syncthreads();
    unsigned long long wexcl = 0;
    for (int w = 0; w < wid; ++w) wexcl += ws[w];
    if (t < nb) bsums[t] = wexcl + v - orig;      // exclusive
    if (t == 1023) {                              // grand total -> bsums[nb]
        unsigned long long tt = 0;
        for (int w = 0; w < 1024 / 64; ++w) tt += ws[w];
        bsums[nb] = tt;
    }
}

// ---------------------------------------------------------------- multi worklist via deterministic multi-prefix slot (NO atomics)
__global__ void uniq_kernel(const unsigned* __restrict__ cnt,
                            const unsigned long long* __restrict__ pairs,
                            const unsigned long long* __restrict__ bsums,
                            uint4* __restrict__ wl, int K) {
    int k = blockIdx.x * blockDim.x + threadIdx.x;
    if (k >= K) return;
    unsigned c = cnt[k];
    if (c < 2) return;                                   // singletons handled point-driven
    unsigned long long pr = pairs[k] + bsums[k >> 11];   // flag==0 since c>=2; EPB=2048
    unsigned start = (unsigned)(pr & F_MASK);
    unsigned rank  = (unsigned)((pr >> F_BITS) & F_MASK);
    unsigned mslot = (unsigned)((pr >> (2 * F_BITS)) & F_MASK);
    wl[mslot] = make_uint4(start, start + c, (unsigned)k, rank);
}

// ---------------------------------------------------------------- scatter point ids (multi only), cnt doubles as cursor (atomicSub)
__global__ void scatter_kernel(const unsigned* __restrict__ keys,
                               const unsigned long long* __restrict__ pairs,
                               const unsigned long long* __restrict__ bsums,
                               unsigned* __restrict__ cnt,
                               unsigned* __restrict__ pointIds, int n) {
    int i = blockIdx.x * blockDim.x + threadIdx.x;
    if (i >= n) return;
    unsigned k = keys[i];
    unsigned long long pr = pairs[k];
    if (pr >> 63) return;                                // singleton — no pid list needed
    unsigned start = (unsigned)((pr + bsums[k >> 11]) & F_MASK);
    unsigned off = atomicSub(&cnt[k], 1u) - 1u;          // c-1, c-2, ..., 0
    pointIds[start + off] = (unsigned)i;
}

// ---------------------------------------------------------------- point-driven: singleton buckets copy their own row
__global__ void __launch_bounds__(256)
point_kernel(const float* __restrict__ feat, const unsigned* __restrict__ keys,
             const unsigned long long* __restrict__ pairs,
             const unsigned long long* __restrict__ bsums,
             float* __restrict__ outF, float* __restrict__ outI, int n) {
    int lane = threadIdx.x & 63;
    int wid  = threadIdx.x >> 6;
    int half = lane >> 5;                 // which of the 2 points this lane serves
    int sub  = lane & 31;                 // float4 slot within the row
    long p = (long)blockIdx.x * 8 + wid * 2 + half;
    if (p >= n) return;
    unsigned key = keys[p];
    unsigned long long pr = pairs[key];
    if (!(pr >> 63)) return;              // not a singleton bucket
    pr += bsums[key >> 11];
    unsigned rank = (unsigned)((pr >> F_BITS) & F_MASK);
    float4 v = ((const float4*)(feat + (size_t)p * C_DIM))[sub];
    ((float4*)(outF + (size_t)rank * C_DIM))[sub] = v;
    if (sub == 0) {
        unsigned bb  = key / YX;
        unsigned rem = key % YX;
        outI[(size_t)rank * 3 + 0] = (float)bb;
        outI[(size_t)rank * 3 + 1] = (float)(rem / X_DIM);
        outI[(size_t)rank * 3 + 2] = (float)(rem % X_DIM);
    }
}

// ---------------------------------------------------------------- multi gather+sum, then pad tail rows (fused, grid-stride)
__global__ void __launch_bounds__(256)
multi_pad_kernel(const float* __restrict__ feat, const unsigned* __restrict__ pointIds,
                 const uint4* __restrict__ wl,
                 const unsigned long long* __restrict__ total,
                 float* __restrict__ outF, float* __restrict__ outI, int n) {
    int lane = threadIdx.x & 63;
    int wid  = threadIdx.x >> 6;
    int half = lane >> 5;
    int sub  = lane & 31;
    unsigned long long tot = *total;
    long nU = (long)((tot >> F_BITS) & F_MASK);
    long m  = (long)((tot >> (2 * F_BITS)) & F_MASK);
    long base   = (long)blockIdx.x * 8 + wid * 2 + half;
    long stride = (long)gridDim.x * 8;
    for (long r = base; r < m; r += stride) {
        uint4 d = wl[r];
        float4 acc = make_float4(0.f, 0.f, 0.f, 0.f);
        for (unsigned j = d.x; j < d.y; ++j) {
            unsigned pid = pointIds[j];
            float4 v = ((const float4*)(feat + (size_t)pid * C_DIM))[sub];
            acc.x += v.x; acc.y += v.y; acc.z += v.z; acc.w += v.w;
        }
        ((float4*)(outF + (size_t)d.w * C_DIM))[sub] = acc;
        if (sub == 0) {
            unsigned key = d.z;
            unsigned bb  = key / YX;
            unsigned rem = key % YX;
            outI[(size_t)d.w * 3 + 0] = (float)bb;
            outI[(size_t)d.w * 3 + 1] = (float)(rem / X_DIM);
            outI[(size_t)d.w * 3 + 2] = (float)(rem % X_DIM);
        }
    }
    for (long r = nU + base; r < n; r += stride) {
        ((float4*)(outF + (size_t)r * C_DIM))[sub] = make_float4(0.f, 0.f, 0.f, 0.f);
        if (sub == 0) {
            outI[(size_t)r * 3 + 0] = -1.0f;
            outI[(size_t)r * 3 + 1] = 467.0f;   // (-1 % YX) // X per numpy floor-mod
            outI[(size_t)r * 3 + 2] = 467.0f;
        }
    }
}

extern "C" void kernel_launch(void* const* d_in, const int* in_sizes, int n_in,
                              void* d_out, int out_size, void* d_ws, size_t ws_size,
                              hipStream_t stream) {
    const float* feat = (const float*)d_in[0];
    const int*   idx  = (const int*)d_in[1];
    const int n = in_sizes[0] / C_DIM;   // 1,000,000
    const int K = KSPACE;

    // workspace layout (256B aligned slices)
    char* ws = (char*)d_ws;
    size_t off = 0;
    auto take = [&](size_t bytes) {
        size_t cur = off;
        off = (off + bytes + 255) & ~(size_t)255;
        return cur;
    };
    size_t o_cnt    = take((size_t)K * 4);        // count per key (later reused as scatter cursor)
    size_t o_keys   = take((size_t)n * 4);        // cached keys per point
    size_t o_pairs  = take((size_t)K * 8);        // packed scan prefixes + singleton flag
    size_t o_bsums  = take((size_t)(NBLK + 1) * 8);
    size_t o_pids   = take((size_t)n * 4);        // point ids (multi buckets only)
    size_t o_wl     = take((size_t)(n / 2 + 1) * 16);  // worklist {start,end,key,rank}

    unsigned*           cnt    = (unsigned*)(ws + o_cnt);
    unsigned*           keys   = (unsigned*)(ws + o_keys);
    unsigned long long* pairs  = (unsigned long long*)(ws + o_pairs);
    unsigned long long* bsums  = (unsigned long long*)(ws + o_bsums);
    unsigned*           pids   = (unsigned*)(ws + o_pids);
    uint4*              wl     = (uint4*)(ws + o_wl);

    float* outF = (float*)d_out;
    float* outI = outF + (size_t)n * C_DIM;

    // 1. zero cnt
    zero_u32<<<(K + 255) / 256, 256, 0, stream>>>(cnt, K);
    // 2. histogram + cache keys
    hist_kernel<<<(n + 255) / 256, 256, 0, stream>>>(idx, cnt, keys, n);
    // 3-4. two-level exclusive scan of packed (count|unique|multi)
    scan1_kernel<<<NBLK, WG, 0, stream>>>(cnt, pairs, bsums, K);
    scan2_kernel<<<1, 1024, 0, stream>>>(bsums, NBLK);
    // 5. multi-bucket worklist (atomic-free, deterministic slots)
    uniq_kernel<<<(K + 255) / 256, 256, 0, stream>>>(cnt, pairs, bsums, wl, K);
    // 6. scatter point ids (multi only; consumes cnt as cursor)
    scatter_kernel<<<(n + 255) / 256, 256, 0, stream>>>(keys, pairs, bsums, cnt, pids, n);
    // 7. point-driven singleton copy
    point_kernel<<<(n + 7) / 8, 256, 0, stream>>>(feat, keys, pairs, bsums, outF, outI, n);
    // 8. multi gather+sum + pad tail (fused)
    multi_pad_kernel<<<2048, 256, 0, stream>>>(feat, pids, wl, bsums + NBLK, outF, outI, n);
}

// Round 5
// 329.206 us; speedup vs baseline: 2.1487x; 1.2127x over previous
//
#include <hip/hip_runtime.h>

// Problem constants (match reference)
#define N_PTS   1000000
#define C_DIM   128
#define B_DIM   8
#define Y_DIM   468
#define X_DIM   468
#define YX      (Y_DIM * X_DIM)         // 219024
#define KSPACE  (B_DIM * YX)            // 1752192 dense key space

// Scan config
#define WG   256
#define EPT  8
#define EPB  (WG * EPT)                 // 2048 elements per scan block
#define NBLK ((KSPACE + EPB - 1) / EPB) // 856

// 3-field packed scan element: [0:21) point-count, [21:42) unique-count, [42:63) multi-count
#define F_BITS 21
#define F_MASK 0x1FFFFFu
#define SINGLE_FLAG (1ull << 63)

__device__ __forceinline__ unsigned long long shfl_up_u64(unsigned long long v, int delta) {
    unsigned lo = (unsigned)v;
    unsigned hi = (unsigned)(v >> 32);
    lo = __shfl_up(lo, delta, 64);
    hi = __shfl_up(hi, delta, 64);
    return ((unsigned long long)hi << 32) | lo;
}

// ---------------------------------------------------------------- zero
__global__ void zero_u32(unsigned* __restrict__ p, int n) {
    int i = blockIdx.x * blockDim.x + threadIdx.x;
    if (i < n) p[i] = 0u;
}

// ---------------------------------------------------------------- histogram + key cache
__global__ void hist_kernel(const int* __restrict__ idx, unsigned* __restrict__ cnt,
                            unsigned* __restrict__ keys, int n) {
    int i = blockIdx.x * blockDim.x + threadIdx.x;
    if (i >= n) return;
    int4 v = ((const int4*)idx)[i];          // (b, z, y, x)
    unsigned key = (unsigned)(v.x * YX + v.z * X_DIM + v.w);
    keys[i] = key;
    atomicAdd(&cnt[key], 1u);
}

// ---------------------------------------------------------------- scan pass 1: per-block exclusive scan of packed (count|unique|multi)
// pairs[k] = exclusive prefix within block, bit63 = (cnt[k]==1)
__global__ void scan1_kernel(const unsigned* __restrict__ cnt,
                             unsigned long long* __restrict__ pairs,
                             unsigned long long* __restrict__ bsums, int K) {
    int base = blockIdx.x * EPB + threadIdx.x * EPT;
    unsigned long long p[EPT];
    unsigned cc[EPT];
    unsigned long long run = 0;
#pragma unroll
    for (int j = 0; j < EPT; ++j) {
        int k = base + j;
        unsigned c = (k < K) ? cnt[k] : 0u;
        cc[j] = c;
        unsigned long long pr = (unsigned long long)c
                              | ((unsigned long long)(c ? 1u : 0u) << F_BITS)
                              | ((unsigned long long)(c >= 2u ? 1u : 0u) << (2 * F_BITS));
        p[j] = run;                           // exclusive within thread
        run += pr;
    }
    unsigned long long tot = run;
    // inclusive wave scan of thread totals
    int lane = threadIdx.x & 63;
    unsigned long long v = tot;
#pragma unroll
    for (int d = 1; d < 64; d <<= 1) {
        unsigned long long nv = shfl_up_u64(v, d);
        if (lane >= d) v += nv;
    }
    __shared__ unsigned long long wsum[WG / 64];
    int wid = threadIdx.x >> 6;
    if (lane == 63) wsum[wid] = v;
    __syncthreads();
    unsigned long long wexcl = 0;
    for (int w = 0; w < wid; ++w) wexcl += wsum[w];
    unsigned long long texcl = wexcl + v - tot;   // exclusive across threads in block
#pragma unroll
    for (int j = 0; j < EPT; ++j) {
        int k = base + j;
        if (k < K)
            pairs[k] = (texcl + p[j]) | (cc[j] == 1u ? SINGLE_FLAG : 0ull);
    }
    if (threadIdx.x == WG - 1) bsums[blockIdx.x] = wexcl + v;  // block total
}

// ---------------------------------------------------------------- scan pass 2: exclusive scan of block sums (single block, nb <= 1024)
__global__ void scan2_kernel(unsigned long long* __restrict__ bsums, int nb) {
    int t = threadIdx.x;
    unsigned long long orig = (t < nb) ? bsums[t] : 0ull;
    unsigned long long v = orig;
    int lane = t & 63;
#pragma unroll
    for (int d = 1; d < 64; d <<= 1) {
        unsigned long long nv = shfl_up_u64(v, d);
        if (lane >= d) v += nv;
    }
    __shared__ unsigned long long ws[1024 / 64];
    int wid = t >> 6;
    if (lane == 63) ws[wid] = v;
    __syncthreads();
    unsigned long long wexcl = 0;
    for (int w = 0; w < wid; ++w) wexcl += ws[w];
    if (t < nb) bsums[t] = wexcl + v - orig;      // exclusive
    if (t == 1023) {                              // grand total -> bsums[nb]
        unsigned long long tt = 0;
        for (int w = 0; w < 1024 / 64; ++w) tt += ws[w];
        bsums[nb] = tt;
    }
}

// ---------------------------------------------------------------- multi worklist via deterministic multi-prefix slot (NO atomics)
__global__ void uniq_kernel(const unsigned* __restrict__ cnt,
                            const unsigned long long* __restrict__ pairs,
                            const unsigned long long* __restrict__ bsums,
                            uint4* __restrict__ wl, int K) {
    int k = blockIdx.x * blockDim.x + threadIdx.x;
    if (k >= K) return;
    unsigned c = cnt[k];
    if (c < 2) return;                                   // singletons handled point-driven
    unsigned long long pr = pairs[k] + bsums[k >> 11];   // flag==0 since c>=2; EPB=2048
    unsigned start = (unsigned)(pr & F_MASK);
    unsigned rank  = (unsigned)((pr >> F_BITS) & F_MASK);
    unsigned mslot = (unsigned)((pr >> (2 * F_BITS)) & F_MASK);
    wl[mslot] = make_uint4(start, start + c, (unsigned)k, rank);
}

// ---------------------------------------------------------------- fused per-point pass: singleton row copy OR pid scatter
// 4 points per wave: quarter = lane>>4, sub = lane&15 (each thread covers
// float4 slots sub and sub+16 of its point's 32-slot row)
__global__ void __launch_bounds__(256)
pointscatter_kernel(const float* __restrict__ feat, const unsigned* __restrict__ keys,
                    const unsigned long long* __restrict__ pairs,
                    const unsigned long long* __restrict__ bsums,
                    unsigned* __restrict__ cnt, unsigned* __restrict__ pids,
                    float* __restrict__ outF, float* __restrict__ outI, int n) {
    int lane = threadIdx.x & 63;
    int wid  = threadIdx.x >> 6;
    int q    = lane >> 4;                 // which of the 4 points this lane serves
    int sub  = lane & 15;                 // float4 slot within the row (plus sub+16)
    long p = (long)blockIdx.x * 16 + wid * 4 + q;
    if (p >= n) return;
    unsigned key = keys[p];
    unsigned long long pr = pairs[key];
    if (pr >> 63) {                       // singleton: copy own row to out[rank]
        pr += bsums[key >> 11];
        unsigned rank = (unsigned)((pr >> F_BITS) & F_MASK);
        const float4* src = (const float4*)(feat + (size_t)p * C_DIM);
        float4*       dst = (float4*)(outF + (size_t)rank * C_DIM);
        float4 v0 = src[sub];
        float4 v1 = src[sub + 16];
        dst[sub]      = v0;
        dst[sub + 16] = v1;
        if (sub == 0) {
            unsigned bb  = key / YX;
            unsigned rem = key % YX;
            outI[(size_t)rank * 3 + 0] = (float)bb;
            outI[(size_t)rank * 3 + 1] = (float)(rem / X_DIM);
            outI[(size_t)rank * 3 + 2] = (float)(rem % X_DIM);
        }
    } else if (sub == 0) {                // multi: scatter pid (cnt doubles as cursor)
        unsigned start = (unsigned)((pr + bsums[key >> 11]) & F_MASK);
        unsigned off = atomicSub(&cnt[key], 1u) - 1u;    // c-1, ..., 0
        pids[start + off] = (unsigned)p;
    }
}

// ---------------------------------------------------------------- multi gather+sum (2-way pid unroll), then pad tail rows
__global__ void __launch_bounds__(256)
multi_pad_kernel(const float* __restrict__ feat, const unsigned* __restrict__ pointIds,
                 const uint4* __restrict__ wl,
                 const unsigned long long* __restrict__ total,
                 float* __restrict__ outF, float* __restrict__ outI, int n) {
    int lane = threadIdx.x & 63;
    int wid  = threadIdx.x >> 6;
    int half = lane >> 5;
    int sub  = lane & 31;
    unsigned long long tot = *total;
    long nU = (long)((tot >> F_BITS) & F_MASK);
    long m  = (long)((tot >> (2 * F_BITS)) & F_MASK);
    long base   = (long)blockIdx.x * 8 + wid * 2 + half;
    long stride = (long)gridDim.x * 8;
    for (long r = base; r < m; r += stride) {
        uint4 d = wl[r];
        float4 acc = make_float4(0.f, 0.f, 0.f, 0.f);
        unsigned j = d.x, e = d.y;
        for (; j + 1 < e; j += 2) {       // paired: two independent row gathers in flight
            unsigned pid0 = pointIds[j];
            unsigned pid1 = pointIds[j + 1];
            float4 v0 = ((const float4*)(feat + (size_t)pid0 * C_DIM))[sub];
            float4 v1 = ((const float4*)(feat + (size_t)pid1 * C_DIM))[sub];
            acc.x += v0.x + v1.x; acc.y += v0.y + v1.y;
            acc.z += v0.z + v1.z; acc.w += v0.w + v1.w;
        }
        if (j < e) {
            unsigned pid = pointIds[j];
            float4 v = ((const float4*)(feat + (size_t)pid * C_DIM))[sub];
            acc.x += v.x; acc.y += v.y; acc.z += v.z; acc.w += v.w;
        }
        ((float4*)(outF + (size_t)d.w * C_DIM))[sub] = acc;
        if (sub == 0) {
            unsigned key = d.z;
            unsigned bb  = key / YX;
            unsigned rem = key % YX;
            outI[(size_t)d.w * 3 + 0] = (float)bb;
            outI[(size_t)d.w * 3 + 1] = (float)(rem / X_DIM);
            outI[(size_t)d.w * 3 + 2] = (float)(rem % X_DIM);
        }
    }
    for (long r = nU + base; r < n; r += stride) {
        ((float4*)(outF + (size_t)r * C_DIM))[sub] = make_float4(0.f, 0.f, 0.f, 0.f);
        if (sub == 0) {
            outI[(size_t)r * 3 + 0] = -1.0f;
            outI[(size_t)r * 3 + 1] = 467.0f;   // (-1 % YX) // X per numpy floor-mod
            outI[(size_t)r * 3 + 2] = 467.0f;
        }
    }
}

extern "C" void kernel_launch(void* const* d_in, const int* in_sizes, int n_in,
                              void* d_out, int out_size, void* d_ws, size_t ws_size,
                              hipStream_t stream) {
    const float* feat = (const float*)d_in[0];
    const int*   idx  = (const int*)d_in[1];
    const int n = in_sizes[0] / C_DIM;   // 1,000,000
    const int K = KSPACE;

    // workspace layout (256B aligned slices)
    char* ws = (char*)d_ws;
    size_t off = 0;
    auto take = [&](size_t bytes) {
        size_t cur = off;
        off = (off + bytes + 255) & ~(size_t)255;
        return cur;
    };
    size_t o_cnt    = take((size_t)K * 4);        // count per key (later reused as scatter cursor)
    size_t o_keys   = take((size_t)n * 4);        // cached keys per point
    size_t o_pairs  = take((size_t)K * 8);        // packed scan prefixes + singleton flag
    size_t o_bsums  = take((size_t)(NBLK + 1) * 8);
    size_t o_pids   = take((size_t)n * 4);        // point ids (multi buckets only)
    size_t o_wl     = take((size_t)(n / 2 + 1) * 16);  // worklist {start,end,key,rank}

    unsigned*           cnt    = (unsigned*)(ws + o_cnt);
    unsigned*           keys   = (unsigned*)(ws + o_keys);
    unsigned long long* pairs  = (unsigned long long*)(ws + o_pairs);
    unsigned long long* bsums  = (unsigned long long*)(ws + o_bsums);
    unsigned*           pids   = (unsigned*)(ws + o_pids);
    uint4*              wl     = (uint4*)(ws + o_wl);

    float* outF = (float*)d_out;
    float* outI = outF + (size_t)n * C_DIM;

    // 1. zero cnt
    zero_u32<<<(K + 255) / 256, 256, 0, stream>>>(cnt, K);
    // 2. histogram + cache keys
    hist_kernel<<<(n + 255) / 256, 256, 0, stream>>>(idx, cnt, keys, n);
    // 3-4. two-level exclusive scan of packed (count|unique|multi)
    scan1_kernel<<<NBLK, WG, 0, stream>>>(cnt, pairs, bsums, K);
    scan2_kernel<<<1, 1024, 0, stream>>>(bsums, NBLK);
    // 5. multi-bucket worklist (atomic-free, deterministic slots)
    uniq_kernel<<<(K + 255) / 256, 256, 0, stream>>>(cnt, pairs, bsums, wl, K);
    // 6. fused per-point pass: singleton row copy OR pid scatter
    pointscatter_kernel<<<(n + 15) / 16, 256, 0, stream>>>(feat, keys, pairs, bsums,
                                                           cnt, pids, outF, outI, n);
    // 7. multi gather+sum + pad tail (fused)
    multi_pad_kernel<<<2048, 256, 0, stream>>>(feat, pids, wl, bsums + NBLK, outF, outI, n);
}

// Round 6
// 327.883 us; speedup vs baseline: 2.1573x; 1.0040x over previous
//
#include <hip/hip_runtime.h>

// Problem constants (match reference)
#define N_PTS   1000000
#define C_DIM   128
#define B_DIM   8
#define Y_DIM   468
#define X_DIM   468
#define YX      (Y_DIM * X_DIM)         // 219024
#define KSPACE  (B_DIM * YX)            // 1752192 dense key space

// Scan config
#define WG   256
#define EPT  8
#define EPB  (WG * EPT)                 // 2048 elements per scan block
#define NBLK ((KSPACE + EPB - 1) / EPB) // 856

// 3-field packed scan element: [0:21) point-count, [21:42) unique-count, [42:63) multi-count
#define F_BITS 21
#define F_MASK 0x1FFFFFu
#define SINGLE_FLAG (1ull << 63)

__device__ __forceinline__ unsigned long long shfl_up_u64(unsigned long long v, int delta) {
    unsigned lo = (unsigned)v;
    unsigned hi = (unsigned)(v >> 32);
    lo = __shfl_up(lo, delta, 64);
    hi = __shfl_up(hi, delta, 64);
    return ((unsigned long long)hi << 32) | lo;
}

// ---------------------------------------------------------------- zero
__global__ void zero_u32(unsigned* __restrict__ p, int n) {
    int i = blockIdx.x * blockDim.x + threadIdx.x;
    if (i < n) p[i] = 0u;
}

// ---------------------------------------------------------------- histogram + key cache
__global__ void hist_kernel(const int* __restrict__ idx, unsigned* __restrict__ cnt,
                            unsigned* __restrict__ keys, int n) {
    int i = blockIdx.x * blockDim.x + threadIdx.x;
    if (i >= n) return;
    int4 v = ((const int4*)idx)[i];          // (b, z, y, x)
    unsigned key = (unsigned)(v.x * YX + v.z * X_DIM + v.w);
    keys[i] = key;
    atomicAdd(&cnt[key], 1u);
}

// ---------------------------------------------------------------- scan pass 1: per-block exclusive scan of packed (count|unique|multi)
// pairs[k] = exclusive prefix within block, bit63 = (cnt[k]==1)
__global__ void scan1_kernel(const unsigned* __restrict__ cnt,
                             unsigned long long* __restrict__ pairs,
                             unsigned long long* __restrict__ bsums, int K) {
    int base = blockIdx.x * EPB + threadIdx.x * EPT;
    unsigned long long p[EPT];
    unsigned cc[EPT];
    unsigned long long run = 0;
#pragma unroll
    for (int j = 0; j < EPT; ++j) {
        int k = base + j;
        unsigned c = (k < K) ? cnt[k] : 0u;
        cc[j] = c;
        unsigned long long pr = (unsigned long long)c
                              | ((unsigned long long)(c ? 1u : 0u) << F_BITS)
                              | ((unsigned long long)(c >= 2u ? 1u : 0u) << (2 * F_BITS));
        p[j] = run;                           // exclusive within thread
        run += pr;
    }
    unsigned long long tot = run;
    // inclusive wave scan of thread totals
    int lane = threadIdx.x & 63;
    unsigned long long v = tot;
#pragma unroll
    for (int d = 1; d < 64; d <<= 1) {
        unsigned long long nv = shfl_up_u64(v, d);
        if (lane >= d) v += nv;
    }
    __shared__ unsigned long long wsum[WG / 64];
    int wid = threadIdx.x >> 6;
    if (lane == 63) wsum[wid] = v;
    __syncthreads();
    unsigned long long wexcl = 0;
    for (int w = 0; w < wid; ++w) wexcl += wsum[w];
    unsigned long long texcl = wexcl + v - tot;   // exclusive across threads in block
#pragma unroll
    for (int j = 0; j < EPT; ++j) {
        int k = base + j;
        if (k < K)
            pairs[k] = (texcl + p[j]) | (cc[j] == 1u ? SINGLE_FLAG : 0ull);
    }
    if (threadIdx.x == WG - 1) bsums[blockIdx.x] = wexcl + v;  // block total
}

// ---------------------------------------------------------------- scan pass 2: exclusive scan of block sums (single block, nb <= 1024)
__global__ void scan2_kernel(unsigned long long* __restrict__ bsums, int nb) {
    int t = threadIdx.x;
    unsigned long long orig = (t < nb) ? bsums[t] : 0ull;
    unsigned long long v = orig;
    int lane = t & 63;
#pragma unroll
    for (int d = 1; d < 64; d <<= 1) {
        unsigned long long nv = shfl_up_u64(v, d);
        if (lane >= d) v += nv;
    }
    __shared__ unsigned long long ws[1024 / 64];
    int wid = t >> 6;
    if (lane == 63) ws[wid] = v;
    __syncthreads();
    unsigned long long wexcl = 0;
    for (int w = 0; w < wid; ++w) wexcl += ws[w];
    if (t < nb) bsums[t] = wexcl + v - orig;      // exclusive
    if (t == 1023) {                              // grand total -> bsums[nb]
        unsigned long long tt = 0;
        for (int w = 0; w < 1024 / 64; ++w) tt += ws[w];
        bsums[nb] = tt;
    }
}

// ---------------------------------------------------------------- per-key pass (sorted): write outI for ALL unique keys (sequential
// in rank), and build multi worklist via deterministic multi-prefix slot
__global__ void uniq_kernel(const unsigned* __restrict__ cnt,
                            const unsigned long long* __restrict__ pairs,
                            const unsigned long long* __restrict__ bsums,
                            uint4* __restrict__ wl, float* __restrict__ outI, int K) {
    int k = blockIdx.x * blockDim.x + threadIdx.x;
    if (k >= K) return;
    unsigned c = cnt[k];
    if (c == 0) return;
    unsigned long long pr = (pairs[k] & ~SINGLE_FLAG) + bsums[k >> 11];  // EPB=2048
    unsigned rank = (unsigned)((pr >> F_BITS) & F_MASK);
    // sequential-in-rank index write (ranks ascend with k)
    unsigned bb  = (unsigned)k / YX;
    unsigned rem = (unsigned)k % YX;
    outI[(size_t)rank * 3 + 0] = (float)bb;
    outI[(size_t)rank * 3 + 1] = (float)(rem / X_DIM);
    outI[(size_t)rank * 3 + 2] = (float)(rem % X_DIM);
    if (c >= 2) {
        unsigned start = (unsigned)(pr & F_MASK);
        unsigned mslot = (unsigned)((pr >> (2 * F_BITS)) & F_MASK);
        wl[mslot] = make_uint4(start, start + c, (unsigned)k, rank);
    }
}

// ---------------------------------------------------------------- fused per-point pass: singleton row copy OR pid scatter
// 4 points per wave: quarter = lane>>4, sub = lane&15 (each thread covers
// float4 slots sub and sub+16 of its point's 32-slot row)
__global__ void __launch_bounds__(256)
pointscatter_kernel(const float* __restrict__ feat, const unsigned* __restrict__ keys,
                    const unsigned long long* __restrict__ pairs,
                    const unsigned long long* __restrict__ bsums,
                    unsigned* __restrict__ cnt, unsigned* __restrict__ pids,
                    float* __restrict__ outF, int n) {
    int lane = threadIdx.x & 63;
    int wid  = threadIdx.x >> 6;
    int q    = lane >> 4;                 // which of the 4 points this lane serves
    int sub  = lane & 15;                 // float4 slot within the row (plus sub+16)
    long p = (long)blockIdx.x * 16 + wid * 4 + q;
    if (p >= n) return;
    unsigned key = keys[p];
    unsigned long long pr = pairs[key];
    if (pr >> 63) {                       // singleton: copy own row to out[rank]
        pr += bsums[key >> 11];
        unsigned rank = (unsigned)((pr >> F_BITS) & F_MASK);
        const float4* src = (const float4*)(feat + (size_t)p * C_DIM);
        float4*       dst = (float4*)(outF + (size_t)rank * C_DIM);
        float4 v0 = src[sub];
        float4 v1 = src[sub + 16];
        dst[sub]      = v0;
        dst[sub + 16] = v1;
    } else if (sub == 0) {                // multi: scatter pid (cnt doubles as cursor)
        unsigned start = (unsigned)((pr + bsums[key >> 11]) & F_MASK);
        unsigned off = atomicSub(&cnt[key], 1u) - 1u;    // c-1, ..., 0
        pids[start + off] = (unsigned)p;
    }
}

// ---------------------------------------------------------------- multi gather+sum (2-way pid unroll), then pad tail rows
__global__ void __launch_bounds__(256)
multi_pad_kernel(const float* __restrict__ feat, const unsigned* __restrict__ pointIds,
                 const uint4* __restrict__ wl,
                 const unsigned long long* __restrict__ total,
                 float* __restrict__ outF, float* __restrict__ outI, int n) {
    int lane = threadIdx.x & 63;
    int wid  = threadIdx.x >> 6;
    int half = lane >> 5;
    int sub  = lane & 31;
    unsigned long long tot = *total;
    long nU = (long)((tot >> F_BITS) & F_MASK);
    long m  = (long)((tot >> (2 * F_BITS)) & F_MASK);
    long base   = (long)blockIdx.x * 8 + wid * 2 + half;
    long stride = (long)gridDim.x * 8;
    for (long r = base; r < m; r += stride) {
        uint4 d = wl[r];
        float4 acc = make_float4(0.f, 0.f, 0.f, 0.f);
        unsigned j = d.x, e = d.y;
        for (; j + 1 < e; j += 2) {       // paired: two independent row gathers in flight
            unsigned pid0 = pointIds[j];
            unsigned pid1 = pointIds[j + 1];
            float4 v0 = ((const float4*)(feat + (size_t)pid0 * C_DIM))[sub];
            float4 v1 = ((const float4*)(feat + (size_t)pid1 * C_DIM))[sub];
            acc.x += v0.x + v1.x; acc.y += v0.y + v1.y;
            acc.z += v0.z + v1.z; acc.w += v0.w + v1.w;
        }
        if (j < e) {
            unsigned pid = pointIds[j];
            float4 v = ((const float4*)(feat + (size_t)pid * C_DIM))[sub];
            acc.x += v.x; acc.y += v.y; acc.z += v.z; acc.w += v.w;
        }
        ((float4*)(outF + (size_t)d.w * C_DIM))[sub] = acc;
    }
    for (long r = nU + base; r < n; r += stride) {
        ((float4*)(outF + (size_t)r * C_DIM))[sub] = make_float4(0.f, 0.f, 0.f, 0.f);
        if (sub == 0) {
            outI[(size_t)r * 3 + 0] = -1.0f;
            outI[(size_t)r * 3 + 1] = 467.0f;   // (-1 % YX) // X per numpy floor-mod
            outI[(size_t)r * 3 + 2] = 467.0f;
        }
    }
}

extern "C" void kernel_launch(void* const* d_in, const int* in_sizes, int n_in,
                              void* d_out, int out_size, void* d_ws, size_t ws_size,
                              hipStream_t stream) {
    const float* feat = (const float*)d_in[0];
    const int*   idx  = (const int*)d_in[1];
    const int n = in_sizes[0] / C_DIM;   // 1,000,000
    const int K = KSPACE;

    // workspace layout (256B aligned slices)
    char* ws = (char*)d_ws;
    size_t off = 0;
    auto take = [&](size_t bytes) {
        size_t cur = off;
        off = (off + bytes + 255) & ~(size_t)255;
        return cur;
    };
    size_t o_cnt    = take((size_t)K * 4);        // count per key (later reused as scatter cursor)
    size_t o_keys   = take((size_t)n * 4);        // cached keys per point
    size_t o_pairs  = take((size_t)K * 8);        // packed scan prefixes + singleton flag
    size_t o_bsums  = take((size_t)(NBLK + 1) * 8);
    size_t o_pids   = take((size_t)n * 4);        // point ids (multi buckets only)
    size_t o_wl     = take((size_t)(n / 2 + 1) * 16);  // worklist {start,end,key,rank}

    unsigned*           cnt    = (unsigned*)(ws + o_cnt);
    unsigned*           keys   = (unsigned*)(ws + o_keys);
    unsigned long long* pairs  = (unsigned long long*)(ws + o_pairs);
    unsigned long long* bsums  = (unsigned long long*)(ws + o_bsums);
    unsigned*           pids   = (unsigned*)(ws + o_pids);
    uint4*              wl     = (uint4*)(ws + o_wl);

    float* outF = (float*)d_out;
    float* outI = outF + (size_t)n * C_DIM;

    // 1. zero cnt
    zero_u32<<<(K + 255) / 256, 256, 0, stream>>>(cnt, K);
    // 2. histogram + cache keys
    hist_kernel<<<(n + 255) / 256, 256, 0, stream>>>(idx, cnt, keys, n);
    // 3-4. two-level exclusive scan of packed (count|unique|multi)
    scan1_kernel<<<NBLK, WG, 0, stream>>>(cnt, pairs, bsums, K);
    scan2_kernel<<<1, 1024, 0, stream>>>(bsums, NBLK);
    // 5. per-key pass: sequential outI writes + multi worklist
    uniq_kernel<<<(K + 255) / 256, 256, 0, stream>>>(cnt, pairs, bsums, wl, outI, K);
    // 6. fused per-point pass: singleton row copy OR pid scatter
    pointscatter_kernel<<<(n + 15) / 16, 256, 0, stream>>>(feat, keys, pairs, bsums,
                                                           cnt, pids, outF, n);
    // 7. multi gather+sum + pad tail (fused)
    multi_pad_kernel<<<4096, 256, 0, stream>>>(feat, pids, wl, bsums + NBLK, outF, outI, n);
}

// Round 8
// 278.955 us; speedup vs baseline: 2.5357x; 1.1754x over previous
//
#include <hip/hip_runtime.h>

// Problem constants (match reference)
#define N_PTS   1000000
#define C_DIM   128
#define B_DIM   8
#define Y_DIM   468
#define X_DIM   468
#define YX      (Y_DIM * X_DIM)         // 219024
#define KSPACE  (B_DIM * YX)            // 1752192 dense key space

// Scan config
#define WG   256
#define EPT  8
#define EPB  (WG * EPT)                 // 2048 elements per scan block
#define NBLK ((KSPACE + EPB - 1) / EPB) // 856

// 3-field packed scan element: [0:21) point-count, [21:42) unique-count, [42:63) multi-count
#define F_BITS 21
#define F_MASK 0x1FFFFFu
#define SINGLE_FLAG (1ull << 63)

#define PAD_BLOCKS 2048

// native vector type for nontemporal builtins (HIP's float4 is a class)
typedef float f4 __attribute__((ext_vector_type(4)));

__device__ __forceinline__ unsigned long long shfl_up_u64(unsigned long long v, int delta) {
    unsigned lo = (unsigned)v;
    unsigned hi = (unsigned)(v >> 32);
    lo = __shfl_up(lo, delta, 64);
    hi = __shfl_up(hi, delta, 64);
    return ((unsigned long long)hi << 32) | lo;
}

// ---------------------------------------------------------------- zero
__global__ void zero_u32(unsigned* __restrict__ p, int n) {
    int i = blockIdx.x * blockDim.x + threadIdx.x;
    if (i < n) p[i] = 0u;
}

// ---------------------------------------------------------------- histogram + key cache
__global__ void hist_kernel(const int* __restrict__ idx, unsigned* __restrict__ cnt,
                            unsigned* __restrict__ keys, int n) {
    int i = blockIdx.x * blockDim.x + threadIdx.x;
    if (i >= n) return;
    int4 v = ((const int4*)idx)[i];          // (b, z, y, x)
    unsigned key = (unsigned)(v.x * YX + v.z * X_DIM + v.w);
    keys[i] = key;
    atomicAdd(&cnt[key], 1u);
}

// ---------------------------------------------------------------- scan pass 1: per-block exclusive scan of packed (count|unique|multi)
// pairs[k] = exclusive prefix within block, bit63 = (cnt[k]==1)
__global__ void scan1_kernel(const unsigned* __restrict__ cnt,
                             unsigned long long* __restrict__ pairs,
                             unsigned long long* __restrict__ bsums, int K) {
    int base = blockIdx.x * EPB + threadIdx.x * EPT;
    unsigned long long p[EPT];
    unsigned cc[EPT];
    unsigned long long run = 0;
#pragma unroll
    for (int j = 0; j < EPT; ++j) {
        int k = base + j;
        unsigned c = (k < K) ? cnt[k] : 0u;
        cc[j] = c;
        unsigned long long pr = (unsigned long long)c
                              | ((unsigned long long)(c ? 1u : 0u) << F_BITS)
                              | ((unsigned long long)(c >= 2u ? 1u : 0u) << (2 * F_BITS));
        p[j] = run;                           // exclusive within thread
        run += pr;
    }
    unsigned long long tot = run;
    // inclusive wave scan of thread totals
    int lane = threadIdx.x & 63;
    unsigned long long v = tot;
#pragma unroll
    for (int d = 1; d < 64; d <<= 1) {
        unsigned long long nv = shfl_up_u64(v, d);
        if (lane >= d) v += nv;
    }
    __shared__ unsigned long long wsum[WG / 64];
    int wid = threadIdx.x >> 6;
    if (lane == 63) wsum[wid] = v;
    __syncthreads();
    unsigned long long wexcl = 0;
    for (int w = 0; w < wid; ++w) wexcl += wsum[w];
    unsigned long long texcl = wexcl + v - tot;   // exclusive across threads in block
#pragma unroll
    for (int j = 0; j < EPT; ++j) {
        int k = base + j;
        if (k < K)
            pairs[k] = (texcl + p[j]) | (cc[j] == 1u ? SINGLE_FLAG : 0ull);
    }
    if (threadIdx.x == WG - 1) bsums[blockIdx.x] = wexcl + v;  // block total
}

// ---------------------------------------------------------------- scan pass 2: exclusive scan of block sums (single block, nb <= 1024)
__global__ void scan2_kernel(unsigned long long* __restrict__ bsums, int nb) {
    int t = threadIdx.x;
    unsigned long long orig = (t < nb) ? bsums[t] : 0ull;
    unsigned long long v = orig;
    int lane = t & 63;
#pragma unroll
    for (int d = 1; d < 64; d <<= 1) {
        unsigned long long nv = shfl_up_u64(v, d);
        if (lane >= d) v += nv;
    }
    __shared__ unsigned long long ws[1024 / 64];
    int wid = t >> 6;
    if (lane == 63) ws[wid] = v;
    __syncthreads();
    unsigned long long wexcl = 0;
    for (int w = 0; w < wid; ++w) wexcl += ws[w];
    if (t < nb) bsums[t] = wexcl + v - orig;      // exclusive
    if (t == 1023) {                              // grand total -> bsums[nb]
        unsigned long long tt = 0;
        for (int w = 0; w < 1024 / 64; ++w) tt += ws[w];
        bsums[nb] = tt;
    }
}

// ---------------------------------------------------------------- per-key pass (sorted): write outI for ALL unique keys (sequential
// in rank), and build multi worklist via deterministic multi-prefix slot
__global__ void uniq_kernel(const unsigned* __restrict__ cnt,
                            const unsigned long long* __restrict__ pairs,
                            const unsigned long long* __restrict__ bsums,
                            uint4* __restrict__ wl, float* __restrict__ outI, int K) {
    int k = blockIdx.x * blockDim.x + threadIdx.x;
    if (k >= K) return;
    unsigned c = cnt[k];
    if (c == 0) return;
    unsigned long long pr = (pairs[k] & ~SINGLE_FLAG) + bsums[k >> 11];  // EPB=2048
    unsigned rank = (unsigned)((pr >> F_BITS) & F_MASK);
    // sequential-in-rank index write (ranks ascend with k)
    unsigned bb  = (unsigned)k / YX;
    unsigned rem = (unsigned)k % YX;
    outI[(size_t)rank * 3 + 0] = (float)bb;
    outI[(size_t)rank * 3 + 1] = (float)(rem / X_DIM);
    outI[(size_t)rank * 3 + 2] = (float)(rem % X_DIM);
    if (c >= 2) {
        unsigned start = (unsigned)(pr & F_MASK);
        unsigned mslot = (unsigned)((pr >> (2 * F_BITS)) & F_MASK);
        wl[mslot] = make_uint4(start, start + c, (unsigned)k, rank);
    }
}

// ---------------------------------------------------------------- fused per-point pass + pad fill
// Point blocks: 8 points per wave (8 lanes/point, 4 float4 slots per lane).
// Pad blocks (appended to grid): stream zero rows [nU, n) — no dependency
// on pids, overlaps the latency-bound point pass with pure-BW writes.
__global__ void __launch_bounds__(256)
pointscatter_pad_kernel(const float* __restrict__ feat, const unsigned* __restrict__ keys,
                        const unsigned long long* __restrict__ pairs,
                        const unsigned long long* __restrict__ bsums,
                        unsigned* __restrict__ cnt, unsigned* __restrict__ pids,
                        float* __restrict__ outF, float* __restrict__ outI,
                        const unsigned long long* __restrict__ total,
                        int n, int pointBlocks) {
    int lane = threadIdx.x & 63;
    int wid  = threadIdx.x >> 6;
    int e    = lane >> 3;                 // point / row within wave's 8
    int sub  = lane & 7;                  // float4 slots sub, sub+8, sub+16, sub+24
    if ((int)blockIdx.x < pointBlocks) {
        long p = (long)blockIdx.x * 32 + wid * 8 + e;
        if (p >= n) return;
        unsigned key = keys[p];
        unsigned long long pr = pairs[key];
        if (pr >> 63) {                   // singleton: copy own row to out[rank]
            pr += bsums[key >> 11];
            unsigned rank = (unsigned)((pr >> F_BITS) & F_MASK);
            const f4* src = (const f4*)(feat + (size_t)p * C_DIM);
            f4*       dst = (f4*)(outF + (size_t)rank * C_DIM);
            f4 v0 = __builtin_nontemporal_load(src + sub);
            f4 v1 = __builtin_nontemporal_load(src + sub + 8);
            f4 v2 = __builtin_nontemporal_load(src + sub + 16);
            f4 v3 = __builtin_nontemporal_load(src + sub + 24);
            __builtin_nontemporal_store(v0, dst + sub);
            __builtin_nontemporal_store(v1, dst + sub + 8);
            __builtin_nontemporal_store(v2, dst + sub + 16);
            __builtin_nontemporal_store(v3, dst + sub + 24);
        } else if (sub == 0) {            // multi: scatter pid (cnt doubles as cursor)
            unsigned start = (unsigned)((pr + bsums[key >> 11]) & F_MASK);
            unsigned off = atomicSub(&cnt[key], 1u) - 1u;    // c-1, ..., 0
            pids[start + off] = (unsigned)p;
        }
    } else {
        // pad rows [nU, n): zeros + (-1, 467, 467)
        unsigned long long tot = *total;
        long nU = (long)((tot >> F_BITS) & F_MASK);
        long base   = nU + (long)((int)blockIdx.x - pointBlocks) * 32 + wid * 8 + e;
        long stride = (long)(gridDim.x - pointBlocks) * 32;
        f4 z = (f4)(0.f);
        for (long r = base; r < n; r += stride) {
            f4* dst = (f4*)(outF + (size_t)r * C_DIM);
            __builtin_nontemporal_store(z, dst + sub);
            __builtin_nontemporal_store(z, dst + sub + 8);
            __builtin_nontemporal_store(z, dst + sub + 16);
            __builtin_nontemporal_store(z, dst + sub + 24);
            if (sub == 0) {
                outI[(size_t)r * 3 + 0] = -1.0f;
                outI[(size_t)r * 3 + 1] = 467.0f;   // (-1 % YX) // X per numpy floor-mod
                outI[(size_t)r * 3 + 2] = 467.0f;
            }
        }
    }
}

// ---------------------------------------------------------------- multi gather+sum: 4 rows/wave, paired-pid unroll
__global__ void __launch_bounds__(256)
multi_kernel(const float* __restrict__ feat, const unsigned* __restrict__ pointIds,
             const uint4* __restrict__ wl,
             const unsigned long long* __restrict__ total,
             float* __restrict__ outF) {
    int lane = threadIdx.x & 63;
    int wid  = threadIdx.x >> 6;
    int rq   = lane >> 4;                 // row within wave's 4
    int sub  = lane & 15;                 // float4 slots sub, sub+16
    long m = (long)(((*total) >> (2 * F_BITS)) & F_MASK);
    long base   = (long)blockIdx.x * 16 + wid * 4 + rq;
    long stride = (long)gridDim.x * 16;
    for (long r = base; r < m; r += stride) {
        uint4 d = wl[r];
        f4 a0 = (f4)(0.f);
        f4 a1 = (f4)(0.f);
        unsigned j = d.x, e = d.y;
        for (; j + 1 < e; j += 2) {       // paired: 4 independent row-half loads in flight
            unsigned p0 = pointIds[j];
            unsigned p1 = pointIds[j + 1];
            const f4* s0 = (const f4*)(feat + (size_t)p0 * C_DIM);
            const f4* s1 = (const f4*)(feat + (size_t)p1 * C_DIM);
            f4 v00 = __builtin_nontemporal_load(s0 + sub);
            f4 v01 = __builtin_nontemporal_load(s0 + sub + 16);
            f4 v10 = __builtin_nontemporal_load(s1 + sub);
            f4 v11 = __builtin_nontemporal_load(s1 + sub + 16);
            a0 += v00 + v10;
            a1 += v01 + v11;
        }
        if (j < e) {
            unsigned p0 = pointIds[j];
            const f4* s0 = (const f4*)(feat + (size_t)p0 * C_DIM);
            f4 v00 = __builtin_nontemporal_load(s0 + sub);
            f4 v01 = __builtin_nontemporal_load(s0 + sub + 16);
            a0 += v00;
            a1 += v01;
        }
        f4* dst = (f4*)(outF + (size_t)d.w * C_DIM);
        __builtin_nontemporal_store(a0, dst + sub);
        __builtin_nontemporal_store(a1, dst + sub + 16);
    }
}

extern "C" void kernel_launch(void* const* d_in, const int* in_sizes, int n_in,
                              void* d_out, int out_size, void* d_ws, size_t ws_size,
                              hipStream_t stream) {
    const float* feat = (const float*)d_in[0];
    const int*   idx  = (const int*)d_in[1];
    const int n = in_sizes[0] / C_DIM;   // 1,000,000
    const int K = KSPACE;

    // workspace layout (256B aligned slices)
    char* ws = (char*)d_ws;
    size_t off = 0;
    auto take = [&](size_t bytes) {
        size_t cur = off;
        off = (off + bytes + 255) & ~(size_t)255;
        return cur;
    };
    size_t o_cnt    = take((size_t)K * 4);        // count per key (later reused as scatter cursor)
    size_t o_keys   = take((size_t)n * 4);        // cached keys per point
    size_t o_pairs  = take((size_t)K * 8);        // packed scan prefixes + singleton flag
    size_t o_bsums  = take((size_t)(NBLK + 1) * 8);
    size_t o_pids   = take((size_t)n * 4);        // point ids (multi buckets only)
    size_t o_wl     = take((size_t)(n / 2 + 1) * 16);  // worklist {start,end,key,rank}

    unsigned*           cnt    = (unsigned*)(ws + o_cnt);
    unsigned*           keys   = (unsigned*)(ws + o_keys);
    unsigned long long* pairs  = (unsigned long long*)(ws + o_pairs);
    unsigned long long* bsums  = (unsigned long long*)(ws + o_bsums);
    unsigned*           pids   = (unsigned*)(ws + o_pids);
    uint4*              wl     = (uint4*)(ws + o_wl);

    float* outF = (float*)d_out;
    float* outI = outF + (size_t)n * C_DIM;

    // 1. zero cnt
    zero_u32<<<(K + 255) / 256, 256, 0, stream>>>(cnt, K);
    // 2. histogram + cache keys
    hist_kernel<<<(n + 255) / 256, 256, 0, stream>>>(idx, cnt, keys, n);
    // 3-4. two-level exclusive scan of packed (count|unique|multi)
    scan1_kernel<<<NBLK, WG, 0, stream>>>(cnt, pairs, bsums, K);
    scan2_kernel<<<1, 1024, 0, stream>>>(bsums, NBLK);
    // 5. per-key pass: sequential outI writes + multi worklist
    uniq_kernel<<<(K + 255) / 256, 256, 0, stream>>>(cnt, pairs, bsums, wl, outI, K);
    // 6. fused per-point pass (singleton copy / pid scatter) + pad fill
    {
        int pointBlocks = (n + 31) / 32;
        pointscatter_pad_kernel<<<pointBlocks + PAD_BLOCKS, 256, 0, stream>>>(
            feat, keys, pairs, bsums, cnt, pids, outF, outI, bsums + NBLK, n, pointBlocks);
    }
    // 7. multi gather+sum
    multi_kernel<<<4096, 256, 0, stream>>>(feat, pids, wl, bsums + NBLK, outF);
}